// Round 1
// 1398.030 us; speedup vs baseline: 1.1135x; 1.1135x over previous
//
#include <hip/hip_runtime.h>
#include <hip/hip_bf16.h>

// Problem constants (match reference)
#define DIMN 100
#define NPATH 8192
#define NT 50
#define HW 256
#define RRATE 0.05f

typedef __hip_bfloat16 bf16;
typedef _Float16 h16;
typedef __attribute__((ext_vector_type(8))) _Float16 h16x8;
typedef __attribute__((ext_vector_type(4))) float f32x4;

// dtype-flag-branched raw-input loader: f32 != 0 -> fp32 array, else bf16 array
__device__ __forceinline__ float ldin(const void* p, long i, int f32) {
    return f32 ? ((const float*)p)[i] : __bfloat162float(((const bf16*)p)[i]);
}

// ---------------- probe input dtype ----------------
__global__ void probe_kernel(const void* tgp, int* flag) {
    if (threadIdx.x == 0 && blockIdx.x == 0) {
        const unsigned short* u = (const unsigned short*)tgp;
        *flag = (u[1] == 0) ? 1 : 0;   // fp32: high half of 0.0f == 0
    }
}

// ---------------- init: S_carry (f32) from S0; Vt[k][d] = V[d][k] (f32) ----------
__global__ void init_kernel(const void* S0, float* S_carry,
                            const void* V, float* Vt, const int* dflag) {
    const int f = *dflag;
    const long i = (long)blockIdx.x * blockDim.x + threadIdx.x;
    if (i < (long)NPATH * DIMN) S_carry[i] = ldin(S0, i, f);
    if (i < DIMN * DIMN) {
        const long d = i / DIMN, k = i % DIMN;
        Vt[k * DIMN + d] = ldin(V, d * DIMN + k, f);
    }
}

// ---------------- pack all MLP weights to fp16 W^T[n][k] layouts ----------------
// Pg0[256][128]  (k<101 from Wg_in[k][n]); Pgh 3x[256][256]; Pgout[128][256] (n<100)
// Pv0[256][128]; Pvh 3x[256][256]. Total 491520 h16.
__global__ void pack_kernel(const void* Wg_in, const void* Wg_h, const void* Wg_out,
                            const void* Wv_in, const void* Wv_h,
                            h16* __restrict__ P, const int* __restrict__ dflag)
{
    const int f = *dflag;
    const long i = (long)blockIdx.x * blockDim.x + threadIdx.x;
    if (i >= 491520) return;
    float v;
    if (i < 32768) {                      // Pg0
        const int n = i >> 7, k = i & 127;
        v = (k < 101) ? ldin(Wg_in, (long)k * 256 + n, f) : 0.f;
    } else if (i < 229376) {              // Pgh
        const long j = i - 32768;
        const int l = (int)(j >> 16), r = (int)(j & 65535), n = r >> 8, k = r & 255;
        v = ldin(Wg_h, ((long)l * 256 + k) * 256 + n, f);
    } else if (i < 262144) {              // Pgout
        const long j = i - 229376;
        const int n = (int)(j >> 8), k = (int)(j & 255);
        v = (n < 100) ? ldin(Wg_out, (long)k * 100 + n, f) : 0.f;
    } else if (i < 294912) {              // Pv0
        const long j = i - 262144;
        const int n = (int)(j >> 7), k = (int)(j & 127);
        v = (k < 101) ? ldin(Wv_in, (long)k * 256 + n, f) : 0.f;
    } else {                              // Pvh
        const long j = i - 294912;
        const int l = (int)(j >> 16), r = (int)(j & 65535), n = r >> 8, k = r & 255;
        v = ldin(Wv_h, ((long)l * 256 + k) * 256 + n, f);
    }
    P[i] = (h16)v;
}

// ---------------- fp32 GEMM (only for D = dW @ V^T) ----------------
template <bool A_RAW>
__global__ __launch_bounds__(256)
void gemm_kernel(const void* A, long aOff, int K,
                 const float* __restrict__ Bw, int N,
                 float* __restrict__ Cout, const int* __restrict__ dflag)
{
    const int f = *dflag;
    __shared__ float As[8][128];
    __shared__ float Bs[8][128];
    const int tid = threadIdx.x;
    const int tx = tid & 15, ty = tid >> 4;
    const long rowBase = (long)blockIdx.x * 128;
    const int colBase = blockIdx.y * 128;

    float acc[8][8];
#pragma unroll
    for (int i = 0; i < 8; i++)
#pragma unroll
        for (int j = 0; j < 8; j++) acc[i][j] = 0.f;

    for (int k0 = 0; k0 < K; k0 += 8) {
        {
            const int l = tid * 4;
            const int row = l >> 3;
            const int col = l & 7;
            const long abase = aOff + (rowBase + row) * (long)K + (k0 + col);
#pragma unroll
            for (int q = 0; q < 4; q++)
                As[col + q][row] = (k0 + col + q < K) ? ldin(A, abase + q, f) : 0.f;
        }
#pragma unroll
        for (int q = 0; q < 4; q++) {
            const int l = tid + 256 * q;
            const int kk = l >> 7, col = l & 127;
            const int gk = k0 + kk, gc = colBase + col;
            Bs[kk][col] = (gk < K && gc < N) ? Bw[(long)gk * N + gc] : 0.f;
        }
        __syncthreads();
#pragma unroll
        for (int kk = 0; kk < 8; kk++) {
            float a[8], b[8];
            const float4 a0 = *(const float4*)&As[kk][ty * 8];
            const float4 a1 = *(const float4*)&As[kk][ty * 8 + 4];
            const float4 b0 = *(const float4*)&Bs[kk][tx * 8];
            const float4 b1 = *(const float4*)&Bs[kk][tx * 8 + 4];
            a[0]=a0.x;a[1]=a0.y;a[2]=a0.z;a[3]=a0.w;a[4]=a1.x;a[5]=a1.y;a[6]=a1.z;a[7]=a1.w;
            b[0]=b0.x;b[1]=b0.y;b[2]=b0.z;b[3]=b0.w;b[4]=b1.x;b[5]=b1.y;b[6]=b1.z;b[7]=b1.w;
#pragma unroll
            for (int i = 0; i < 8; i++)
#pragma unroll
                for (int j = 0; j < 8; j++)
                    acc[i][j] += a[i] * b[j];
        }
        __syncthreads();
    }

#pragma unroll
    for (int i = 0; i < 8; i++) {
        const long row = rowBase + ty * 8 + i;
        const int colb = colBase + tx * 8;
        if (colb + 7 < N) {
            float4* cp = (float4*)(Cout + row * (long)N + colb);
            cp[0] = make_float4(acc[i][0], acc[i][1], acc[i][2], acc[i][3]);
            cp[1] = make_float4(acc[i][4], acc[i][5], acc[i][6], acc[i][7]);
        } else {
#pragma unroll
            for (int j = 0; j < 8; j++)
                if (colb + j < N) Cout[row * (long)N + colb + j] = acc[i][j];
        }
    }
}

// ---------------- chunked S scan: emits fp16 S (padded 104), vol in-place over D --
// vol = s*D*sqrt(h)  (includes sqrt(h)); S_new = s*(1+r*h) + vol.
__global__ __launch_bounds__(256)
void scan_chunk_kernel(float* __restrict__ S_carry, float* __restrict__ D,
                       const void* tgp, h16* __restrict__ Sh,
                       int t0, int Cg, void* outBase, h16* __restrict__ Shf,
                       int writeSf, const int* __restrict__ dflag)
{
    const int f = *dflag;
    const long idx = (long)blockIdx.x * blockDim.x + threadIdx.x;
    if (idx >= (long)NPATH * DIMN) return;
    const long b = idx / DIMN;
    const int d = (int)(idx - b * DIMN);
    float s = S_carry[idx];
    for (int lt = 0; lt < Cg; lt++) {
        const int t = t0 + lt;
        const float h = ldin(tgp, t + 1, f) - ldin(tgp, t, f);
        const long off = (long)lt * (NPATH * DIMN) + idx;
        const float vol = s * D[off] * sqrtf(h);
        const long shr = ((long)lt * NPATH + b) * 104;
        Sh[shr + d] = (h16)s;
        if (d < 4) Sh[shr + 100 + d] = (h16)0.f;
        D[off] = vol;
        s = s + RRATE * s * h + vol;
    }
    S_carry[idx] = s;
    if (writeSf) {
        if (f) ((float*)outBase)[NPATH + idx] = s;
        else   ((bf16*)outBase)[NPATH + idx] = __float2bfloat16(s);
        Shf[b * 104 + d] = (h16)s;
        if (d < 4) Shf[b * 104 + 100 + d] = (h16)0.f;
    }
}

// ---------------- fused MFMA fp16 MLP: 64 rows/block, 4 waves split N ----------
// GNET: 5 layers (last N=100 pad 128) + stoch epilogue (dot with vol, fp32).
// VNET: 4 layers + 256->1 dot epilogue. Weights pre-packed W^T[n][k] fp16.
// mfma_f32_16x16x32_f16: A[m=lane&15][k=quad*8+j]; B[k=quad*8+j][n=lane&15];
// C: col=lane&15, row=quad*4+reg.
// B-fragments loaded DIRECTLY global->VGPR (L2-resident shared weights):
//   - no Wl LDS staging -> LDS 75.8K -> 35.8K (2 -> 3-4 blocks/CU)
//   - wave-private B + read-only Hs -> barrier-free k-loop (2 syncs/layer)
//   - register double-buffer (bcur/bnxt) hides L2 latency within-wave
template <bool GNET>
__global__ __launch_bounds__(256, 3)
void mlp16_kernel(const h16* __restrict__ Sh, const float* __restrict__ vol,
                  const h16* __restrict__ P0, const h16* __restrict__ Ph,
                  const h16* __restrict__ Pout,
                  const void* b_in, const void* b_h, const void* b_out,
                  const void* wv_out, const void* tgp, int t0,
                  float* __restrict__ outv, const int* __restrict__ dflag)
{
    const int f = *dflag;
    __shared__ __align__(16) h16 Hs[64][264];     // 33,792 B (stride 264: 2-way-free b128)
    __shared__ float Ps[64][4];
    __shared__ float wvs[256];

    const int tid = threadIdx.x;
    const int w = tid >> 6, lane = tid & 63, quad = lane >> 4, m = lane & 15;
    const long row0 = (long)blockIdx.x * 64;
    const int t = t0 + (int)(row0 >> 13);         // 64 | 8192

    if (!GNET) wvs[tid] = ldin(wv_out, tid, f);

    // ---- stage layer-0 input x=[t,S]: Hs[r][0]=t, [1..100]=S, [101..127]=0 ----
    {
        const int r = tid >> 2, j = tid & 3;
        const h16* src = Sh + (row0 + r) * 104;
        for (int c = j; c < 13; c += 4) {
            const h16x8 v = *(const h16x8*)(src + c * 8);
#pragma unroll
            for (int q = 0; q < 8; q++) {
                const int d = c * 8 + q;
                if (d < 100) Hs[r][1 + d] = v[q];
            }
        }
        if (j == 0) Hs[r][0] = (h16)ldin(tgp, t, f);
        if (j == 1) {
            for (int k = 101; k < 128; k++) Hs[r][k] = (h16)0.f;
        }
    }
    __syncthreads();   // layer-0 staging visible to all waves

    const int NL = GNET ? 5 : 4;
    f32x4 acc[4][4];

    for (int l = 0; l < NL; l++) {
        const int Kp  = (l == 0) ? 128 : 256;
        const int NTW = (l == 4) ? 2 : 4;         // ntiles per wave
        const int nb16 = w * (NTW * 16);
        const h16* P = (l == 0) ? P0 : ((l < 4) ? (Ph + (long)(l - 1) * 65536) : Pout);

#pragma unroll
        for (int mt = 0; mt < 4; mt++)
#pragma unroll
            for (int nt = 0; nt < 4; nt++)
                acc[mt][nt] = (f32x4){0.f, 0.f, 0.f, 0.f};

        // lane's base into W^T[n][k]: rows nb16+nt*16+m, k-slice quad*8
        const h16* pw = P + (long)(nb16 + m) * Kp + quad * 8;
        const int nkt = Kp >> 5;

        h16x8 bcur[4], bnxt[4];
#pragma unroll
        for (int nt = 0; nt < 4; nt++)
            if (nt < NTW)
                bcur[nt] = *(const h16x8*)(pw + (long)nt * 16 * Kp);

        for (int kt = 0; kt < nkt; kt++) {
            if (kt + 1 < nkt) {   // prefetch next k-chunk's B frags (global, L2-hit)
                const h16* pn = pw + (kt + 1) * 32;
#pragma unroll
                for (int nt = 0; nt < 4; nt++)
                    if (nt < NTW)
                        bnxt[nt] = *(const h16x8*)(pn + (long)nt * 16 * Kp);
            }
            const int k0 = kt << 5;
            h16x8 a[4];
#pragma unroll
            for (int mt = 0; mt < 4; mt++)
                a[mt] = *(const h16x8*)&Hs[mt * 16 + m][k0 + quad * 8];
#pragma unroll
            for (int mt = 0; mt < 4; mt++)
#pragma unroll
                for (int nt = 0; nt < 4; nt++)
                    if (nt < NTW)
                        acc[mt][nt] = __builtin_amdgcn_mfma_f32_16x16x32_f16(
                            a[mt], bcur[nt], acc[mt][nt], 0, 0, 0);
            if (kt + 1 < nkt) {
#pragma unroll
                for (int nt = 0; nt < 4; nt++)
                    if (nt < NTW)
                        bcur[nt] = bnxt[nt];
            }
        }

        if (l < 4) {   // bias + ReLU + write back to Hs (wave owns cols nb16..nb16+63)
            __syncthreads();   // all waves done READING Hs this layer
            const void* bp = (l == 0) ? b_in : b_h;
            const long bo = (l == 0) ? 0 : (long)(l - 1) * 256;
#pragma unroll
            for (int nt = 0; nt < 4; nt++) {
                const int col = nb16 + nt * 16 + m;
                const float bb = ldin(bp, bo + col, f);
#pragma unroll
                for (int mt = 0; mt < 4; mt++)
#pragma unroll
                    for (int i = 0; i < 4; i++) {
                        const float x = acc[mt][nt][i] + bb;
                        Hs[mt * 16 + quad * 4 + i][col] = (h16)fmaxf(x, 0.f);
                    }
            }
            __syncthreads();   // writes visible before next layer reads
        }
    }

    if (GNET) {
        // stoch = sum_col grad*vol  (vol already has sqrt(h))
        float p[4][4];
#pragma unroll
        for (int mt = 0; mt < 4; mt++)
#pragma unroll
            for (int i = 0; i < 4; i++) p[mt][i] = 0.f;
#pragma unroll
        for (int nt = 0; nt < 2; nt++) {
            const int col = w * 32 + nt * 16 + m;
            if (col < DIMN) {
                const float bo = ldin(b_out, col, f);
#pragma unroll
                for (int mt = 0; mt < 4; mt++)
#pragma unroll
                    for (int i = 0; i < 4; i++) {
                        const long row = row0 + mt * 16 + quad * 4 + i;
                        p[mt][i] += (acc[mt][nt][i] + bo) * vol[row * DIMN + col];
                    }
            }
        }
#pragma unroll
        for (int mt = 0; mt < 4; mt++)
#pragma unroll
            for (int i = 0; i < 4; i++) {
                float v = p[mt][i];
                v += __shfl_xor(v, 1, 16);
                v += __shfl_xor(v, 2, 16);
                v += __shfl_xor(v, 4, 16);
                v += __shfl_xor(v, 8, 16);
                p[mt][i] = v;
            }
        if (m == 0) {
#pragma unroll
            for (int mt = 0; mt < 4; mt++)
#pragma unroll
                for (int i = 0; i < 4; i++)
                    Ps[mt * 16 + quad * 4 + i][w] = p[mt][i];
        }
        __syncthreads();
        if (tid < 64)
            outv[row0 + tid] = Ps[tid][0] + Ps[tid][1] + Ps[tid][2] + Ps[tid][3];
    } else {
        // v = Hs . w_out + b_out (256 -> 1), 4 threads per row
        const int r = tid & 63, part = tid >> 6;
        float s = 0.f;
#pragma unroll
        for (int c = 0; c < 8; c++) {
            const h16x8 hv = *(const h16x8*)&Hs[r][part * 64 + c * 8];
#pragma unroll
            for (int q = 0; q < 8; q++)
                s += (float)hv[q] * wvs[part * 64 + c * 8 + q];
        }
        Ps[r][part] = s;
        __syncthreads();
        if (tid < 64)
            outv[row0 + tid] = Ps[tid][0] + Ps[tid][1] + Ps[tid][2] + Ps[tid][3]
                               + ldin(b_out, 0, f);
    }
}

// ---------------- final: error accumulation + v_f ----------------
__global__ void final_kernel(const float* __restrict__ v_all, const float* __restrict__ stoch,
                             const void* tgp, void* out, const int* __restrict__ dflag)
{
    const int f = *dflag;
    const int b = blockIdx.x * blockDim.x + threadIdx.x;
    if (b >= NPATH) return;
    float err = 0.f;
    for (int i = 0; i < NT - 1; i++) {
        const float h = ldin(tgp, i + 1, f) - ldin(tgp, i, f);
        const float e = v_all[(i + 1) * NPATH + b] - v_all[i * NPATH + b] * (1.f + RRATE * h)
                        - stoch[i * NPATH + b];
        err += e * e;
    }
    const long eoff = (long)NPATH + (long)NPATH * DIMN;
    const float vf = v_all[(long)(NT - 1) * NPATH + b];
    if (f) {
        ((float*)out)[b] = vf;
        ((float*)out)[eoff + b] = err;
    } else {
        ((bf16*)out)[b] = __float2bfloat16(vf);
        ((bf16*)out)[eoff + b] = __float2bfloat16(err);
    }
}

static inline int imin(int a, int b) { return a < b ? a : b; }

extern "C" void kernel_launch(void* const* d_in, const int* in_sizes, int n_in,
                              void* d_out, int out_size, void* d_ws, size_t ws_size,
                              hipStream_t stream) {
    const void* S0    = d_in[0];
    const void* dW    = d_in[1];
    const void* tg    = d_in[2];
    const void* V     = d_in[3];
    const void* Wg_in = d_in[4];
    const void* bg_in = d_in[5];
    const void* Wg_h  = d_in[6];
    const void* bg_h  = d_in[7];
    const void* Wg_out= d_in[8];
    const void* bg_out= d_in[9];
    const void* Wv_in = d_in[10];
    const void* bv_in = d_in[11];
    const void* Wv_h  = d_in[12];
    const void* bv_h  = d_in[13];
    const void* Wv_out= d_in[14];
    const void* bv_out= d_in[15];

    const size_t SZ_SD  = (size_t)NPATH * DIMN * 4;    // 3.28 MB (f32 per timestep)
    const size_t SZ_SH  = (size_t)NPATH * 104 * 2;     // 1.70 MB (fp16 padded S)

    // ---- carve workspace ----
    char* p = (char*)d_ws;
    auto carve = [&](size_t bytes) -> char* {
        char* r = p;
        p += (bytes + 255) & ~(size_t)255;
        return r;
    };
    int*   dflag     = (int*)carve(256);
    float* S_carry   = (float*)carve(SZ_SD);
    float* Vt        = (float*)carve((size_t)DIMN * DIMN * 4);
    float* v_all     = (float*)carve((size_t)NT * NPATH * 4);
    float* stoch_all = (float*)carve((size_t)(NT - 1) * NPATH * 4);
    h16*   Shf       = (h16*)carve(SZ_SH);
    h16*   Pk        = (h16*)carve((size_t)491520 * 2);     // packed fp16 weights
    const size_t fixed = (size_t)(p - (char*)d_ws);

    // packed-weight sub-pointers
    h16* Pg0   = Pk;
    h16* Pgh   = Pk + 32768;
    h16* Pgout = Pk + 229376;
    h16* Pv0   = Pk + 262144;
    h16* Pvh   = Pk + 294912;

    // adaptive time-chunk: per-timestep = D/vol (f32) + Sh (fp16)
    const size_t perC = SZ_SD + SZ_SH;                       // 4.98 MB
    size_t avail = (ws_size > fixed + 65536) ? (ws_size - fixed - 65536) : 0;
    int C = (int)(avail / perC);
    if (C < 1) C = 1;
    if (C > NT - 1) C = NT - 1;
    float* D_chunk = (float*)carve((size_t)C * SZ_SD);       // vol written in-place
    h16*   Sh      = (h16*)carve((size_t)C * SZ_SH);

    // ---- prep ----
    probe_kernel<<<dim3(1), dim3(64), 0, stream>>>(tg, dflag);
    init_kernel<<<dim3((NPATH * DIMN + 255) / 256), dim3(256), 0, stream>>>(S0, S_carry, V, Vt, dflag);
    pack_kernel<<<dim3(1920), dim3(256), 0, stream>>>(Wg_in, Wg_h, Wg_out, Wv_in, Wv_h, Pk, dflag);

    // ---- chunk loop over timesteps t in [0, 49) ----
    for (int t0 = 0; t0 < NT - 1; t0 += C) {
        const int Cg = imin(C, NT - 1 - t0);
        const int rows = Cg * NPATH;

        // D = dW[t0..t0+Cg) @ V^T
        gemm_kernel<true><<<dim3(rows / 128, 1), 256, 0, stream>>>(
            dW, (long)t0 * NPATH * DIMN, DIMN, Vt, DIMN, D_chunk, dflag);

        // scan: Sh (fp16), vol in-place over D, advance S_carry; S_f + Shf on last chunk
        scan_chunk_kernel<<<dim3((NPATH * DIMN + 255) / 256), 256, 0, stream>>>(
            S_carry, D_chunk, tg, Sh, t0, Cg, d_out, Shf,
            (t0 + Cg == NT - 1) ? 1 : 0, dflag);

        // g-net (MFMA, fused stoch epilogue)
        mlp16_kernel<true><<<dim3(rows / 64), 256, 0, stream>>>(
            Sh, D_chunk, Pg0, Pgh, Pgout, bg_in, bg_h, bg_out,
            nullptr, tg, t0, stoch_all + (long)t0 * NPATH, dflag);

        // v-net (MFMA, fused output dot)
        mlp16_kernel<false><<<dim3(rows / 64), 256, 0, stream>>>(
            Sh, nullptr, Pv0, Pvh, nullptr, bv_in, bv_h, bv_out,
            Wv_out, tg, t0, v_all + (long)t0 * NPATH, dflag);
    }

    // ---- v at t = 49 from Shf ----
    mlp16_kernel<false><<<dim3(NPATH / 64), 256, 0, stream>>>(
        Shf, nullptr, Pv0, Pvh, nullptr, bv_in, bv_h, bv_out,
        Wv_out, tg, NT - 1, v_all + (long)(NT - 1) * NPATH, dflag);

    // ---- error + v_f ----
    final_kernel<<<dim3(NPATH / 256), 256, 0, stream>>>(v_all, stoch_all, tg, d_out, dflag);
}

// Round 2
// 1373.692 us; speedup vs baseline: 1.1332x; 1.0177x over previous
//
#include <hip/hip_runtime.h>
#include <hip/hip_bf16.h>

// Problem constants (match reference)
#define DIMN 100
#define NPATH 8192
#define NT 50
#define HW 256
#define RRATE 0.05f

typedef __hip_bfloat16 bf16;
typedef _Float16 h16;
typedef __attribute__((ext_vector_type(8))) _Float16 h16x8;
typedef __attribute__((ext_vector_type(4))) _Float16 h16x4;
typedef __attribute__((ext_vector_type(4))) float f32x4;

// dtype-flag-branched raw-input loader: f32 != 0 -> fp32 array, else bf16 array
__device__ __forceinline__ float ldin(const void* p, long i, int f32) {
    return f32 ? ((const float*)p)[i] : __bfloat162float(((const bf16*)p)[i]);
}

// ---------------- probe input dtype ----------------
__global__ void probe_kernel(const void* tgp, int* flag) {
    if (threadIdx.x == 0 && blockIdx.x == 0) {
        const unsigned short* u = (const unsigned short*)tgp;
        *flag = (u[1] == 0) ? 1 : 0;   // fp32: high half of 0.0f == 0
    }
}

// ---------------- init: S_carry (f32) from S0; Vt[k][d] = V[d][k] (f32) ----------
__global__ void init_kernel(const void* S0, float* S_carry,
                            const void* V, float* Vt, const int* dflag) {
    const int f = *dflag;
    const long i = (long)blockIdx.x * blockDim.x + threadIdx.x;
    if (i < (long)NPATH * DIMN) S_carry[i] = ldin(S0, i, f);
    if (i < DIMN * DIMN) {
        const long d = i / DIMN, k = i % DIMN;
        Vt[k * DIMN + d] = ldin(V, d * DIMN + k, f);
    }
}

// ---------------- pack all MLP weights to fp16 W^T[n][k] layouts ----------------
// Pg0[256][128]  (k<101 from Wg_in[k][n]); Pgh 3x[256][256]; Pgout[128][256] (n<100)
// Pv0[256][128]; Pvh 3x[256][256]. Total 491520 h16.
__global__ void pack_kernel(const void* Wg_in, const void* Wg_h, const void* Wg_out,
                            const void* Wv_in, const void* Wv_h,
                            h16* __restrict__ P, const int* __restrict__ dflag)
{
    const int f = *dflag;
    const long i = (long)blockIdx.x * blockDim.x + threadIdx.x;
    if (i >= 491520) return;
    float v;
    if (i < 32768) {                      // Pg0
        const int n = i >> 7, k = i & 127;
        v = (k < 101) ? ldin(Wg_in, (long)k * 256 + n, f) : 0.f;
    } else if (i < 229376) {              // Pgh
        const long j = i - 32768;
        const int l = (int)(j >> 16), r = (int)(j & 65535), n = r >> 8, k = r & 255;
        v = ldin(Wg_h, ((long)l * 256 + k) * 256 + n, f);
    } else if (i < 262144) {              // Pgout
        const long j = i - 229376;
        const int n = (int)(j >> 8), k = (int)(j & 255);
        v = (n < 100) ? ldin(Wg_out, (long)k * 100 + n, f) : 0.f;
    } else if (i < 294912) {              // Pv0
        const long j = i - 262144;
        const int n = (int)(j >> 7), k = (int)(j & 127);
        v = (k < 101) ? ldin(Wv_in, (long)k * 256 + n, f) : 0.f;
    } else {                              // Pvh
        const long j = i - 294912;
        const int l = (int)(j >> 16), r = (int)(j & 65535), n = r >> 8, k = r & 255;
        v = ldin(Wv_h, ((long)l * 256 + k) * 256 + n, f);
    }
    P[i] = (h16)v;
}

// ---------------- fp32 GEMM (only for D = dW @ V^T) ----------------
template <bool A_RAW>
__global__ __launch_bounds__(256)
void gemm_kernel(const void* A, long aOff, int K,
                 const float* __restrict__ Bw, int N,
                 float* __restrict__ Cout, const int* __restrict__ dflag)
{
    const int f = *dflag;
    __shared__ float As[8][128];
    __shared__ float Bs[8][128];
    const int tid = threadIdx.x;
    const int tx = tid & 15, ty = tid >> 4;
    const long rowBase = (long)blockIdx.x * 128;
    const int colBase = blockIdx.y * 128;

    float acc[8][8];
#pragma unroll
    for (int i = 0; i < 8; i++)
#pragma unroll
        for (int j = 0; j < 8; j++) acc[i][j] = 0.f;

    for (int k0 = 0; k0 < K; k0 += 8) {
        {
            const int l = tid * 4;
            const int row = l >> 3;
            const int col = l & 7;
            const long abase = aOff + (rowBase + row) * (long)K + (k0 + col);
#pragma unroll
            for (int q = 0; q < 4; q++)
                As[col + q][row] = (k0 + col + q < K) ? ldin(A, abase + q, f) : 0.f;
        }
#pragma unroll
        for (int q = 0; q < 4; q++) {
            const int l = tid + 256 * q;
            const int kk = l >> 7, col = l & 127;
            const int gk = k0 + kk, gc = colBase + col;
            Bs[kk][col] = (gk < K && gc < N) ? Bw[(long)gk * N + gc] : 0.f;
        }
        __syncthreads();
#pragma unroll
        for (int kk = 0; kk < 8; kk++) {
            float a[8], b[8];
            const float4 a0 = *(const float4*)&As[kk][ty * 8];
            const float4 a1 = *(const float4*)&As[kk][ty * 8 + 4];
            const float4 b0 = *(const float4*)&Bs[kk][tx * 8];
            const float4 b1 = *(const float4*)&Bs[kk][tx * 8 + 4];
            a[0]=a0.x;a[1]=a0.y;a[2]=a0.z;a[3]=a0.w;a[4]=a1.x;a[5]=a1.y;a[6]=a1.z;a[7]=a1.w;
            b[0]=b0.x;b[1]=b0.y;b[2]=b0.z;b[3]=b0.w;b[4]=b1.x;b[5]=b1.y;b[6]=b1.z;b[7]=b1.w;
#pragma unroll
            for (int i = 0; i < 8; i++)
#pragma unroll
                for (int j = 0; j < 8; j++)
                    acc[i][j] += a[i] * b[j];
        }
        __syncthreads();
    }

#pragma unroll
    for (int i = 0; i < 8; i++) {
        const long row = rowBase + ty * 8 + i;
        const int colb = colBase + tx * 8;
        if (colb + 7 < N) {
            float4* cp = (float4*)(Cout + row * (long)N + colb);
            cp[0] = make_float4(acc[i][0], acc[i][1], acc[i][2], acc[i][3]);
            cp[1] = make_float4(acc[i][4], acc[i][5], acc[i][6], acc[i][7]);
        } else {
#pragma unroll
            for (int j = 0; j < 8; j++)
                if (colb + j < N) Cout[row * (long)N + colb + j] = acc[i][j];
        }
    }
}

// ---------------- chunked S scan: emits fp16 S (padded 104), vol in-place over D --
// vol = s*D*sqrt(h)  (includes sqrt(h)); S_new = s*(1+r*h) + vol.
__global__ __launch_bounds__(256)
void scan_chunk_kernel(float* __restrict__ S_carry, float* __restrict__ D,
                       const void* tgp, h16* __restrict__ Sh,
                       int t0, int Cg, void* outBase, h16* __restrict__ Shf,
                       int writeSf, const int* __restrict__ dflag)
{
    const int f = *dflag;
    const long idx = (long)blockIdx.x * blockDim.x + threadIdx.x;
    if (idx >= (long)NPATH * DIMN) return;
    const long b = idx / DIMN;
    const int d = (int)(idx - b * DIMN);
    float s = S_carry[idx];
    for (int lt = 0; lt < Cg; lt++) {
        const int t = t0 + lt;
        const float h = ldin(tgp, t + 1, f) - ldin(tgp, t, f);
        const long off = (long)lt * (NPATH * DIMN) + idx;
        const float vol = s * D[off] * sqrtf(h);
        const long shr = ((long)lt * NPATH + b) * 104;
        Sh[shr + d] = (h16)s;
        if (d < 4) Sh[shr + 100 + d] = (h16)0.f;
        D[off] = vol;
        s = s + RRATE * s * h + vol;
    }
    S_carry[idx] = s;
    if (writeSf) {
        if (f) ((float*)outBase)[NPATH + idx] = s;
        else   ((bf16*)outBase)[NPATH + idx] = __float2bfloat16(s);
        Shf[b * 104 + d] = (h16)s;
        if (d < 4) Shf[b * 104 + 100 + d] = (h16)0.f;
    }
}

// ---------------- fused MFMA fp16 MLP: 64 rows/block, 4 waves split N ----------
// TRANSPOSED-OUTPUT scheme: mfma(w_frag, h_frag, acc). Since A- and B-frags share
// the same per-lane pattern (lane&15 = non-k index, quad = k-slice), swapping
// operands gives D with col(lane&15) = H-row, row(quad*4+reg) = output column.
// -> writeback: each lane packs 4 consecutive output cols of ONE row into a
//    single ds_write_b64 (h16x4), bias read as float4 from LDS.
// -> GNET epilogue: lane reads 4 consecutive vol cols as one aligned float4;
//    row-reduce = 2 shfl_xor (quads) instead of 4.
// Weights stream global->VGPR (L2-resident); same-register prefetch for both
// h-frags (LDS) and w-frags (global) keeps arch VGPRs ~56 -> 4 waves/SIMD.
template <bool GNET>
__global__ __launch_bounds__(256, 4)
void mlp16_kernel(const h16* __restrict__ Sh, const float* __restrict__ vol,
                  const h16* __restrict__ P0, const h16* __restrict__ Ph,
                  const h16* __restrict__ Pout,
                  const void* b_in, const void* b_h, const void* b_out,
                  const void* wv_out, const void* tgp, int t0,
                  float* __restrict__ outv, const int* __restrict__ dflag)
{
    const int f = *dflag;
    __shared__ __align__(16) h16 Hs[64][264];       // 33,792 B
    __shared__ __align__(16) float bias_s[4][256];  // 4,096 B (layer biases, f32)
    __shared__ __align__(16) float ex_s[256];       // GNET: padded b_out; VNET: wv_out
    __shared__ float Ps[64][4];
    const int tid = threadIdx.x;
    const int w = tid >> 6, lane = tid & 63, quad = lane >> 4, m = lane & 15;
    const long row0 = (long)blockIdx.x * 64;
    const int t = t0 + (int)(row0 >> 13);           // 64 | 8192

    // ---- preload biases (+ extra vector) into LDS ----
    bias_s[0][tid] = ldin(b_in, tid, f);
    bias_s[1][tid] = ldin(b_h, tid, f);
    bias_s[2][tid] = ldin(b_h, 256 + tid, f);
    bias_s[3][tid] = ldin(b_h, 512 + tid, f);
    if (GNET) {
        if (tid < 128) ex_s[tid] = (tid < DIMN) ? ldin(b_out, tid, f) : 0.f;
    } else {
        ex_s[tid] = ldin(wv_out, tid, f);
    }

    // ---- stage layer-0 input x=[t,S]: Hs[r][0]=t, [1..100]=S, [101..127]=0 ----
    {
        const int r = tid >> 2, j = tid & 3;
        const h16* src = Sh + (row0 + r) * 104;
        for (int c = j; c < 13; c += 4) {
            const h16x8 v = *(const h16x8*)(src + c * 8);
#pragma unroll
            for (int q = 0; q < 8; q++) {
                const int d = c * 8 + q;
                if (d < 100) Hs[r][1 + d] = v[q];
            }
        }
        if (j == 0) Hs[r][0] = (h16)ldin(tgp, t, f);
        if (j == 1) {
            for (int k = 101; k < 128; k++) Hs[r][k] = (h16)0.f;
        }
    }
    __syncthreads();   // staging + bias visible to all waves

    const int NL = GNET ? 5 : 4;
    f32x4 acc[4][4];   // acc[wt][rt]: rows rt*16+m, cols nb16+wt*16+quad*4+reg

    for (int l = 0; l < NL; l++) {
        const int Kp  = (l == 0) ? 128 : 256;
        const int NTW = (l == 4) ? 2 : 4;         // col-tiles per wave
        const int nb16 = w * (NTW * 16);
        const h16* P = (l == 0) ? P0 : ((l < 4) ? (Ph + (long)(l - 1) * 65536) : Pout);

#pragma unroll
        for (int wt = 0; wt < 4; wt++)
#pragma unroll
            for (int rt = 0; rt < 4; rt++)
                acc[wt][rt] = (f32x4){0.f, 0.f, 0.f, 0.f};

        // lane base into W^T[n][k]: row nb16+wt*16+m, k-slice quad*8
        const h16* pw = P + (long)(nb16 + m) * Kp + quad * 8;
        const int nkt = Kp >> 5;

        h16x8 wfrag[4], hfrag[4];
#pragma unroll
        for (int wt = 0; wt < 4; wt++)
            if (wt < NTW)
                wfrag[wt] = *(const h16x8*)(pw + (long)wt * 16 * Kp);
#pragma unroll
        for (int rt = 0; rt < 4; rt++)
            hfrag[rt] = *(const h16x8*)&Hs[rt * 16 + m][quad * 8];

        for (int kt = 0; kt < nkt; kt++) {
#pragma unroll
            for (int wt = 0; wt < 4; wt++)
#pragma unroll
                for (int rt = 0; rt < 4; rt++)
                    if (wt < NTW)
                        acc[wt][rt] = __builtin_amdgcn_mfma_f32_16x16x32_f16(
                            wfrag[wt], hfrag[rt], acc[wt][rt], 0, 0, 0);
            if (kt + 1 < nkt) {   // same-register prefetch: latency hides under MFMAs
                const int k0n = (kt + 1) << 5;
#pragma unroll
                for (int wt = 0; wt < 4; wt++)
                    if (wt < NTW)
                        wfrag[wt] = *(const h16x8*)(pw + (long)wt * 16 * Kp + k0n);
#pragma unroll
                for (int rt = 0; rt < 4; rt++)
                    hfrag[rt] = *(const h16x8*)&Hs[rt * 16 + m][k0n + quad * 8];
            }
        }

        if (l < 4) {   // bias + ReLU + packed b64 writeback
            __syncthreads();   // all waves done READING Hs this layer
#pragma unroll
            for (int wt = 0; wt < 4; wt++) {
                const int cb = nb16 + wt * 16 + quad * 4;
                const float4 bb = *(const float4*)&bias_s[l][cb];
#pragma unroll
                for (int rt = 0; rt < 4; rt++) {
                    const float x0 = fmaxf(acc[wt][rt][0] + bb.x, 0.f);
                    const float x1 = fmaxf(acc[wt][rt][1] + bb.y, 0.f);
                    const float x2 = fmaxf(acc[wt][rt][2] + bb.z, 0.f);
                    const float x3 = fmaxf(acc[wt][rt][3] + bb.w, 0.f);
                    const h16x4 pk = {(h16)x0, (h16)x1, (h16)x2, (h16)x3};
                    *(h16x4*)&Hs[rt * 16 + m][cb] = pk;
                }
            }
            __syncthreads();   // writes visible before next layer reads
        }
    }

    if (GNET) {
        // stoch = sum_col grad*vol  (vol already has sqrt(h))
        float p[4];
#pragma unroll
        for (int rt = 0; rt < 4; rt++) p[rt] = 0.f;
#pragma unroll
        for (int wt = 0; wt < 2; wt++) {
            const int cb = w * 32 + wt * 16 + quad * 4;
            if (cb < DIMN) {   // cb multiple of 4 -> cb<=96 -> cb+3<=99
                const float4 bo = *(const float4*)&ex_s[cb];
#pragma unroll
                for (int rt = 0; rt < 4; rt++) {
                    const long r = row0 + rt * 16 + m;
                    const float4 vv = *(const float4*)&vol[r * DIMN + cb];
                    p[rt] += (acc[wt][rt][0] + bo.x) * vv.x
                           + (acc[wt][rt][1] + bo.y) * vv.y
                           + (acc[wt][rt][2] + bo.z) * vv.z
                           + (acc[wt][rt][3] + bo.w) * vv.w;
                }
            }
        }
#pragma unroll
        for (int rt = 0; rt < 4; rt++) {
            float v = p[rt];
            v += __shfl_xor(v, 16);
            v += __shfl_xor(v, 32);
            if (quad == 0) Ps[rt * 16 + m][w] = v;
        }
        __syncthreads();
        if (tid < 64)
            outv[row0 + tid] = Ps[tid][0] + Ps[tid][1] + Ps[tid][2] + Ps[tid][3];
    } else {
        // v = Hs . w_out + b_out (256 -> 1), 4 threads per row
        const int r = tid & 63, part = tid >> 6;
        float s = 0.f;
#pragma unroll
        for (int c = 0; c < 8; c++) {
            const h16x8 hv = *(const h16x8*)&Hs[r][part * 64 + c * 8];
#pragma unroll
            for (int q = 0; q < 8; q++)
                s += (float)hv[q] * ex_s[part * 64 + c * 8 + q];
        }
        Ps[r][part] = s;
        __syncthreads();
        if (tid < 64)
            outv[row0 + tid] = Ps[tid][0] + Ps[tid][1] + Ps[tid][2] + Ps[tid][3]
                               + ldin(b_out, 0, f);
    }
}

// ---------------- final: error accumulation + v_f ----------------
__global__ void final_kernel(const float* __restrict__ v_all, const float* __restrict__ stoch,
                             const void* tgp, void* out, const int* __restrict__ dflag)
{
    const int f = *dflag;
    const int b = blockIdx.x * blockDim.x + threadIdx.x;
    if (b >= NPATH) return;
    float err = 0.f;
    for (int i = 0; i < NT - 1; i++) {
        const float h = ldin(tgp, i + 1, f) - ldin(tgp, i, f);
        const float e = v_all[(i + 1) * NPATH + b] - v_all[i * NPATH + b] * (1.f + RRATE * h)
                        - stoch[i * NPATH + b];
        err += e * e;
    }
    const long eoff = (long)NPATH + (long)NPATH * DIMN;
    const float vf = v_all[(long)(NT - 1) * NPATH + b];
    if (f) {
        ((float*)out)[b] = vf;
        ((float*)out)[eoff + b] = err;
    } else {
        ((bf16*)out)[b] = __float2bfloat16(vf);
        ((bf16*)out)[eoff + b] = __float2bfloat16(err);
    }
}

static inline int imin(int a, int b) { return a < b ? a : b; }

extern "C" void kernel_launch(void* const* d_in, const int* in_sizes, int n_in,
                              void* d_out, int out_size, void* d_ws, size_t ws_size,
                              hipStream_t stream) {
    const void* S0    = d_in[0];
    const void* dW    = d_in[1];
    const void* tg    = d_in[2];
    const void* V     = d_in[3];
    const void* Wg_in = d_in[4];
    const void* bg_in = d_in[5];
    const void* Wg_h  = d_in[6];
    const void* bg_h  = d_in[7];
    const void* Wg_out= d_in[8];
    const void* bg_out= d_in[9];
    const void* Wv_in = d_in[10];
    const void* bv_in = d_in[11];
    const void* Wv_h  = d_in[12];
    const void* bv_h  = d_in[13];
    const void* Wv_out= d_in[14];
    const void* bv_out= d_in[15];

    const size_t SZ_SD  = (size_t)NPATH * DIMN * 4;    // 3.28 MB (f32 per timestep)
    const size_t SZ_SH  = (size_t)NPATH * 104 * 2;     // 1.70 MB (fp16 padded S)

    // ---- carve workspace ----
    char* p = (char*)d_ws;
    auto carve = [&](size_t bytes) -> char* {
        char* r = p;
        p += (bytes + 255) & ~(size_t)255;
        return r;
    };
    int*   dflag     = (int*)carve(256);
    float* S_carry   = (float*)carve(SZ_SD);
    float* Vt        = (float*)carve((size_t)DIMN * DIMN * 4);
    float* v_all     = (float*)carve((size_t)NT * NPATH * 4);
    float* stoch_all = (float*)carve((size_t)(NT - 1) * NPATH * 4);
    h16*   Shf       = (h16*)carve(SZ_SH);
    h16*   Pk        = (h16*)carve((size_t)491520 * 2);     // packed fp16 weights
    const size_t fixed = (size_t)(p - (char*)d_ws);

    // packed-weight sub-pointers
    h16* Pg0   = Pk;
    h16* Pgh   = Pk + 32768;
    h16* Pgout = Pk + 229376;
    h16* Pv0   = Pk + 262144;
    h16* Pvh   = Pk + 294912;

    // adaptive time-chunk: per-timestep = D/vol (f32) + Sh (fp16)
    const size_t perC = SZ_SD + SZ_SH;                       // 4.98 MB
    size_t avail = (ws_size > fixed + 65536) ? (ws_size - fixed - 65536) : 0;
    int C = (int)(avail / perC);
    if (C < 1) C = 1;
    if (C > NT - 1) C = NT - 1;
    float* D_chunk = (float*)carve((size_t)C * SZ_SD);       // vol written in-place
    h16*   Sh      = (h16*)carve((size_t)C * SZ_SH);

    // ---- prep ----
    probe_kernel<<<dim3(1), dim3(64), 0, stream>>>(tg, dflag);
    init_kernel<<<dim3((NPATH * DIMN + 255) / 256), dim3(256), 0, stream>>>(S0, S_carry, V, Vt, dflag);
    pack_kernel<<<dim3(1920), dim3(256), 0, stream>>>(Wg_in, Wg_h, Wg_out, Wv_in, Wv_h, Pk, dflag);

    // ---- chunk loop over timesteps t in [0, 49) ----
    for (int t0 = 0; t0 < NT - 1; t0 += C) {
        const int Cg = imin(C, NT - 1 - t0);
        const int rows = Cg * NPATH;

        // D = dW[t0..t0+Cg) @ V^T
        gemm_kernel<true><<<dim3(rows / 128, 1), 256, 0, stream>>>(
            dW, (long)t0 * NPATH * DIMN, DIMN, Vt, DIMN, D_chunk, dflag);

        // scan: Sh (fp16), vol in-place over D, advance S_carry; S_f + Shf on last chunk
        scan_chunk_kernel<<<dim3((NPATH * DIMN + 255) / 256), 256, 0, stream>>>(
            S_carry, D_chunk, tg, Sh, t0, Cg, d_out, Shf,
            (t0 + Cg == NT - 1) ? 1 : 0, dflag);

        // g-net (MFMA, fused stoch epilogue)
        mlp16_kernel<true><<<dim3(rows / 64), 256, 0, stream>>>(
            Sh, D_chunk, Pg0, Pgh, Pgout, bg_in, bg_h, bg_out,
            nullptr, tg, t0, stoch_all + (long)t0 * NPATH, dflag);

        // v-net (MFMA, fused output dot)
        mlp16_kernel<false><<<dim3(rows / 64), 256, 0, stream>>>(
            Sh, nullptr, Pv0, Pvh, nullptr, bv_in, bv_h, bv_out,
            Wv_out, tg, t0, v_all + (long)t0 * NPATH, dflag);
    }

    // ---- v at t = 49 from Shf ----
    mlp16_kernel<false><<<dim3(NPATH / 64), 256, 0, stream>>>(
        Shf, nullptr, Pv0, Pvh, nullptr, bv_in, bv_h, bv_out,
        Wv_out, tg, NT - 1, v_all + (long)(NT - 1) * NPATH, dflag);

    // ---- error + v_f ----
    final_kernel<<<dim3(NPATH / 256), 256, 0, stream>>>(v_all, stoch_all, tg, d_out, dflag);
}